// Round 14
// baseline (451.471 us; speedup 1.0000x reference)
//
#include <hip/hip_runtime.h>

#define DEVI __device__ __forceinline__

typedef __attribute__((ext_vector_type(4))) float f32x4;
typedef __attribute__((ext_vector_type(8))) short bf16x8;

typedef const unsigned __attribute__((address_space(1))) as1_u32;
typedef unsigned __attribute__((address_space(3))) as3_u32;

DEVI unsigned fbits(float x){ union{float f;unsigned u;} v; v.f=x; return v.u; }
DEVI float bitsf(unsigned u){ union{unsigned u;float f;} v; v.u=u; return v.f; }
DEVI short bf_rne(float x){ unsigned u=fbits(x); u += 0x7fffu + ((u>>16)&1u); return (short)(u>>16); }

DEVI unsigned pack_hi2(unsigned u0, unsigned u1){
#if __has_builtin(__builtin_amdgcn_perm)
  return __builtin_amdgcn_perm(u1, u0, 0x07060302u);
#else
  return (u0 >> 16) | (u1 & 0xffff0000u);
#endif
}
DEVI unsigned pack_rne2(float a, float b){
  return (unsigned)(unsigned short)bf_rne(a) | ((unsigned)(unsigned short)bf_rne(b) << 16);
}

DEVI void gload16(const short* g, short* s){
  __builtin_amdgcn_global_load_lds((as1_u32*)g, (as3_u32*)s, 16, 0, 0);
}

#define SBAR() { __builtin_amdgcn_sched_barrier(0); asm volatile("" ::: "memory"); \
                 __builtin_amdgcn_s_barrier(); __builtin_amdgcn_sched_barrier(0); }

#define MF(a,b,c) __builtin_amdgcn_mfma_f32_16x16x32_bf16(a,b,c,0,0,0)
#define MROW(M, x) \
  acc[M][0] = MF(x, bb0, acc[M][0]); \
  acc[M][1] = MF(x, bb1, acc[M][1]); \
  acc[M][2] = MF(x, bb2, acc[M][2]); \
  acc[M][3] = MF(x, bb3, acc[M][3]);

// ---------------------------------------------------------------------------
// Split fp32 -> (hi = bf16 truncation, lo = bf16_rne(x - hi)).
// ---------------------------------------------------------------------------
__global__ __launch_bounds__(256)
void k_split(const float* __restrict__ in, short* __restrict__ hi,
             short* __restrict__ lo, const long n4)
{
  long i = (long)blockIdx.x*256 + threadIdx.x;
  const long stride = (long)gridDim.x*256;
  for (; i < n4; i += stride){
    const float4 v = ((const float4*)in)[i];
    const unsigned u0=fbits(v.x), u1=fbits(v.y), u2=fbits(v.z), u3=fbits(v.w);
    ((uint2*)hi)[i] = make_uint2(pack_hi2(u0,u1), pack_hi2(u2,u3));
    const float l0 = v.x - bitsf(u0 & 0xffff0000u);
    const float l1 = v.y - bitsf(u1 & 0xffff0000u);
    const float l2 = v.z - bitsf(u2 & 0xffff0000u);
    const float l3 = v.w - bitsf(u3 & 0xffff0000u);
    ((uint2*)lo)[i] = make_uint2(pack_rne2(l0,l1), pack_rne2(l2,l3));
  }
}

// ---------------------------------------------------------------------------
// Fused 3-combo hi/lo GEMM: 3 phases (AhBh, AlBh, AhBl) per BK=32 k-step.
// 256x256 tile, 512 thr (8 waves 2x4), per-wave 128x64, dbuf 128KB LDS,
// chunk-XOR swizzle (0 bank conflicts, verified R6).
// R11 sync scheme (2 barriers/step, derived from counted-queue analysis):
// all 8 prefetch loads issue at P0 (order hi4,lo4). P0-entry vmcnt(4)+SBAR
// publishes prev-hi (queue 8->4); P1-entry vmcnt(8)+SBAR publishes prev-lo
// (queue 12->8, drains Al AND Bl); P2 needs NO sync (Bl already published),
// so its reads hoist into P1's MFMA shadow. Tail: last step P1 = vmcnt(0).
// ---------------------------------------------------------------------------
template<bool BIAS, bool SPLIT_OUT>
__global__ __launch_bounds__(512, 2)
void k_gemm3(const short* __restrict__ Ah, const short* __restrict__ Al,
             const short* __restrict__ Bh, const short* __restrict__ Bl,
             void* __restrict__ Cv, const float* __restrict__ bias,
             const int K, const int lda, const int ldb, const int ldc,
             const long sAz, const long sBz, const long sCz, const int loOff)
{
  // per buffer (shorts): Ah [0,8192) Al [8192,16384) Bh [16384,24576) Bl [24576,32768)
  __shared__ short LDS[65536];   // 2 buffers x 64KB = 128 KiB

  const int tid = threadIdx.x;
  const int w = tid >> 6, l = tid & 63;
  const int wr = w >> 2, wc = w & 3;
  const int fr = l & 15, h4 = l >> 4;
  const long bz = blockIdx.z;

  // XCD-aware bijective swizzle (nwg % 8 == 0 for all our grids)
  const int nwg = gridDim.x * gridDim.y;
  const int xy  = blockIdx.y * gridDim.x + blockIdx.x;
  const int q8  = nwg >> 3;
  const int sw  = (xy & 7) * q8 + (xy >> 3);
  const int bx  = sw % gridDim.x;
  const int by  = sw / gridDim.x;

  const size_t aOff = (size_t)bz*sAz + (size_t)bx*256*lda;
  const size_t bOff = (size_t)bz*sBz + (size_t)by*256*ldb;

  // staging: 16KB tile = 1024 x 16B chunks; thread handles chunks c0, c0+512.
  // chunk ci -> row ci>>2; LDS slot ci&3 holds logical k-chunk
  // (ci&3)^((ci>>3)&3)  [inverse-swizzled global source, linear LDS dest]
  const int c0 = w*64 + l, c1 = c0 + 512;
  const int k0 = ((c0 & 3) ^ ((c0 >> 3) & 3)) * 8;
  const int k1 = ((c1 & 3) ^ ((c1 >> 3) & 3)) * 8;
  const size_t a0 = (size_t)(c0 >> 2)*lda + k0;
  const size_t a1 = (size_t)(c1 >> 2)*lda + k1;
  const size_t b0 = (size_t)(c0 >> 2)*ldb + k0;
  const size_t b1 = (size_t)(c1 >> 2)*ldb + k1;
  const int dS0 = w*512, dS1 = 4096 + w*512;

  // fragment read bases (shorts): row stride 32; swizzled chunk per lane.
  const int cswz = (h4 ^ ((fr >> 1) & 3)) << 3;
  const int rbA = (wr*128 + fr)*32 + cswz;
  const int rbB = 16384 + (wc*64 + fr)*32 + cswz;

  f32x4 acc[8][4];
#pragma unroll
  for (int m = 0; m < 8; ++m)
#pragma unroll
    for (int n = 0; n < 4; ++n){ acc[m][n][0]=0.f; acc[m][n][1]=0.f; acc[m][n][2]=0.f; acc[m][n][3]=0.f; }

  const short* pAh = Ah + aOff;
  const short* pAl = Al + aOff;
  const short* pBh = Bh + bOff;
  const short* pBl = Bl + bOff;

  // ---- prologue: stage step 0 into buf0 (order: hi x4, lo x4) ----
  gload16(pAh + a0, LDS + dS0);
  gload16(pAh + a1, LDS + dS1);
  gload16(pBh + b0, LDS + 16384 + dS0);
  gload16(pBh + b1, LDS + 16384 + dS1);
  gload16(pAl + a0, LDS + 8192 + dS0);
  gload16(pAl + a1, LDS + 8192 + dS1);
  gload16(pBl + b0, LDS + 24576 + dS0);
  gload16(pBl + b1, LDS + 24576 + dS1);
  pAh += 32; pAl += 32; pBh += 32; pBl += 32;

#define STEP3(CO, PF, V1, V2)                                                \
{                                                                            \
  const short* pA = LDS + (CO) + rbA;                                        \
  const short* pB = LDS + (CO) + rbB;                                        \
  short* dst = LDS + ((CO) ^ 32768);                                         \
  bf16x8 ah0,ah1,ah2,ah3,ah4,ah5,ah6,ah7, bb0,bb1,bb2,bb3;                   \
  /* P0: Ah x Bh  (publish prev-hi; issue ALL next-tile loads) */            \
  asm volatile("s_waitcnt vmcnt(" V1 ")" ::: "memory");                      \
  SBAR();                                                                    \
  if (PF){ gload16(pAh + a0, dst + dS0);                                     \
           gload16(pAh + a1, dst + dS1);                                     \
           gload16(pBh + b0, dst + 16384 + dS0);                             \
           gload16(pBh + b1, dst + 16384 + dS1);                             \
           gload16(pAl + a0, dst + 8192 + dS0);                              \
           gload16(pAl + a1, dst + 8192 + dS1);                              \
           gload16(pBl + b0, dst + 24576 + dS0);                             \
           gload16(pBl + b1, dst + 24576 + dS1);                             \
           pAh += 32; pAl += 32; pBh += 32; pBl += 32; }                     \
  bb0 = *(const bf16x8*)(pB);                                                \
  bb1 = *(const bf16x8*)(pB + 512);                                          \
  bb2 = *(const bf16x8*)(pB + 1024);                                         \
  bb3 = *(const bf16x8*)(pB + 1536);                                         \
  ah0 = *(const bf16x8*)(pA);                                                \
  ah1 = *(const bf16x8*)(pA + 512);                                          \
  ah2 = *(const bf16x8*)(pA + 1024);                                         \
  ah3 = *(const bf16x8*)(pA + 1536);                                         \
  ah4 = *(const bf16x8*)(pA + 2048);                                         \
  ah5 = *(const bf16x8*)(pA + 2560);                                         \
  ah6 = *(const bf16x8*)(pA + 3072);                                         \
  ah7 = *(const bf16x8*)(pA + 3584);                                         \
  __builtin_amdgcn_s_setprio(1);                                             \
  MROW(0,ah0) MROW(1,ah1) MROW(2,ah2) MROW(3,ah3)                            \
  MROW(4,ah4) MROW(5,ah5) MROW(6,ah6) MROW(7,ah7)                            \
  __builtin_amdgcn_s_setprio(0);                                             \
  /* P1: Al x Bh  (publish prev-lo: covers Al AND Bl) */                     \
  asm volatile("s_waitcnt vmcnt(" V2 ")" ::: "memory");                      \
  SBAR();                                                                    \
  {                                                                          \
    bf16x8 al0 = *(const bf16x8*)(pA + 8192);                                \
    bf16x8 al1 = *(const bf16x8*)(pA + 8192 + 512);                          \
    bf16x8 al2 = *(const bf16x8*)(pA + 8192 + 1024);                         \
    bf16x8 al3 = *(const bf16x8*)(pA + 8192 + 1536);                         \
    bf16x8 al4 = *(const bf16x8*)(pA + 8192 + 2048);                         \
    bf16x8 al5 = *(const bf16x8*)(pA + 8192 + 2560);                         \
    bf16x8 al6 = *(const bf16x8*)(pA + 8192 + 3072);                         \
    bf16x8 al7 = *(const bf16x8*)(pA + 8192 + 3584);                         \
    __builtin_amdgcn_s_setprio(1);                                           \
    MROW(0,al0) MROW(1,al1) MROW(2,al2) MROW(3,al3)                          \
    MROW(4,al4) MROW(5,al5) MROW(6,al6) MROW(7,al7)                          \
    __builtin_amdgcn_s_setprio(0);                                           \
  }                                                                          \
  /* P2: Ah x Bl — no sync needed; Bl published by P1's vmcnt+SBAR */        \
  bb0 = *(const bf16x8*)(pB + 8192);                                         \
  bb1 = *(const bf16x8*)(pB + 8192 + 512);                                   \
  bb2 = *(const bf16x8*)(pB + 8192 + 1024);                                  \
  bb3 = *(const bf16x8*)(pB + 8192 + 1536);                                  \
  __builtin_amdgcn_s_setprio(1);                                             \
  MROW(0,ah0) MROW(1,ah1) MROW(2,ah2) MROW(3,ah3)                            \
  MROW(4,ah4) MROW(5,ah5) MROW(6,ah6) MROW(7,ah7)                            \
  __builtin_amdgcn_s_setprio(0);                                             \
}

  const int nk = K >> 5;   // k-steps of 32 (even for all our K)
#pragma unroll 1
  for (int it = 0; it < nk - 2; it += 2){
    STEP3(0,     1, "4", "8")
    STEP3(32768, 1, "4", "8")
  }
  STEP3(0,     1, "4", "8")
  STEP3(32768, 0, "4", "0")

#undef STEP3

  // ---- epilogue: C/D layout col = lane&15, row = (lane>>4)*4 + j ----
  const int rr = h4*4;
  if constexpr (SPLIT_OUT){
    short* Ch = (short*)Cv + (size_t)bz*sCz
              + (size_t)(bx*256 + wr*128)*ldc + by*256 + wc*64;
    short* Cl = Ch + loOff;
#pragma unroll
    for (int n = 0; n < 4; ++n){
      const int col = n*16 + fr;
      const float bv = BIAS ? bias[by*256 + wc*64 + col] : 0.f;
#pragma unroll
      for (int m = 0; m < 8; ++m)
#pragma unroll
        for (int j = 0; j < 4; ++j){
          const float v = acc[m][n][j] + bv;
          const unsigned uh = fbits(v) & 0xffff0000u;
          const size_t idx = (size_t)(m*16 + rr + j)*ldc + col;
          Ch[idx] = (short)(uh >> 16);
          Cl[idx] = bf_rne(v - bitsf(uh));
        }
    }
  } else {
    float* C = (float*)Cv + (size_t)bz*sCz
             + (size_t)(bx*256 + wr*128)*ldc + by*256 + wc*64;
#pragma unroll
    for (int n = 0; n < 4; ++n){
      const int col = n*16 + fr;
      const float bv = BIAS ? bias[by*256 + wc*64 + col] : 0.f;
#pragma unroll
      for (int m = 0; m < 8; ++m)
#pragma unroll
        for (int j = 0; j < 4; ++j)
          C[(size_t)(m*16 + rr + j)*ldc + col] = acc[m][n][j] + bv;
    }
  }
}

// ---------------------------------------------------------------------------
// Plain bf16 1-pass GEMM (K4): R3/R6-proven 8-phase 256x256 BK=64 structure
// with st_16x32 swizzle + counted vmcnt (0 bank conflicts measured).
// UNCHANGED from R10 (proven best for K4).
// ---------------------------------------------------------------------------
__global__ __launch_bounds__(512, 2)
void k_gemm1(const short* __restrict__ Ah, const short* __restrict__ Bh,
             void* __restrict__ Cv,
             const int K, const int lda, const int ldb, const int ldc,
             const long sAz, const long sBz, const long sCz)
{
  __shared__ short LDS[65536];

  const int tid = threadIdx.x;
  const int w = tid >> 6, l = tid & 63;
  const int wr = w >> 2, wc = w & 3;
  const int fr = l & 15, h4 = l >> 4;
  const long bz = blockIdx.z;

  const int nwg = gridDim.x * gridDim.y;
  const int xy  = blockIdx.y * gridDim.x + blockIdx.x;
  const int q8  = nwg >> 3;
  const int sw  = (xy & 7) * q8 + (xy >> 3);
  const int bx  = sw % gridDim.x;
  const int by  = sw / gridDim.x;

  const size_t aOff = (size_t)bz*sAz + (size_t)bx*256*lda;
  const size_t bOff = (size_t)bz*sBz + (size_t)by*256*ldb;

  const int sch = (((l & 7) ^ ((l >> 3) & 7)) << 3);
  const int rA0 = wr*128 + (w & 3)*8 + (l >> 3);
  int aoffg[4];
#pragma unroll
  for (int q2 = 0; q2 < 4; ++q2) aoffg[q2] = (rA0 + 32*q2)*lda;
  const int rB0 = wc*64 + (w >> 2)*8 + (l >> 3);
  int boffg[4];
#pragma unroll
  for (int j2 = 0; j2 < 4; ++j2) boffg[j2] = (rB0 + 16*j2)*ldb;
  const int dAu = wr*8192 + (w & 3)*512;
  const int dBu = 16384 + wc*4096 + (w >> 2)*512;

  const int rbA = (wr*128 + fr)*64;
  const int rbB = 16384 + (wc*64 + fr)*64;
  const int c08 = ((h4     ) ^ (l & 7)) << 3;
  const int c18 = ((h4 + 4 ) ^ (l & 7)) << 3;

  f32x4 acc[8][4];
#pragma unroll
  for (int m = 0; m < 8; ++m)
#pragma unroll
    for (int n = 0; n < 4; ++n){ acc[m][n][0]=0.f; acc[m][n][1]=0.f; acc[m][n][2]=0.f; acc[m][n][3]=0.f; }

  const short* Asrc = Ah + aOff + sch;
  const short* Bsrc = Bh + bOff + sch;

  {
    short* dB0 = LDS + dBu;
    short* dA0 = LDS + dAu;
    gload16(Bsrc + boffg[0], dB0);
    gload16(Bsrc + boffg[1], dB0 + 1024);
    gload16(Bsrc + boffg[2], dB0 + 2048);
    gload16(Bsrc + boffg[3], dB0 + 3072);
    gload16(Asrc + aoffg[0], dA0);
    gload16(Asrc + aoffg[1], dA0 + 2048);
    gload16(Asrc + aoffg[2], dA0 + 4096);
    gload16(Asrc + aoffg[3], dA0 + 6144);
  }
  Asrc += 64; Bsrc += 64;
  asm volatile("s_waitcnt vmcnt(2)" ::: "memory");
  SBAR();

#define TILE(CO, PF, VA, VB)                                                 \
{                                                                            \
  const short* pA = LDS + (CO) + rbA;                                        \
  const short* pB = LDS + (CO) + rbB;                                        \
  short* dAp = LDS + ((CO)^32768) + dAu;                                     \
  short* dBp = LDS + ((CO)^32768) + dBu;                                     \
  bf16x8 aA,aB,aC,aD, bb0,bb1,bb2,bb3;                                       \
  if (PF){ gload16(Bsrc + boffg[0], dBp); gload16(Bsrc + boffg[1], dBp + 1024); } \
  bb0 = *(const bf16x8*)(pB +        c08);                                   \
  bb1 = *(const bf16x8*)(pB + 1024 + c08);                                   \
  bb2 = *(const bf16x8*)(pB + 2048 + c08);                                   \
  bb3 = *(const bf16x8*)(pB + 3072 + c08);                                   \
  aA  = *(const bf16x8*)(pA +        c08);                                   \
  aB  = *(const bf16x8*)(pA + 1024 + c08);                                   \
  aC  = *(const bf16x8*)(pA + 2048 + c08);                                   \
  aD  = *(const bf16x8*)(pA + 3072 + c08);                                   \
  SBAR();                                                                    \
  __builtin_amdgcn_s_setprio(1);                                             \
  MROW(0,aA) MROW(1,aB) MROW(2,aC) MROW(3,aD)                                \
  __builtin_amdgcn_s_setprio(0);                                             \
  asm volatile("s_waitcnt vmcnt(" VA ")" ::: "memory");                      \
  SBAR();                                                                    \
  if (PF){ gload16(Bsrc + boffg[2], dBp + 2048); gload16(Bsrc + boffg[3], dBp + 3072); } \
  aA = *(const bf16x8*)(pA + 4096 + c08);                                    \
  aB = *(const bf16x8*)(pA + 5120 + c08);                                    \
  aC = *(const bf16x8*)(pA + 6144 + c08);                                    \
  aD = *(const bf16x8*)(pA + 7168 + c08);                                    \
  SBAR();                                                                    \
  __builtin_amdgcn_s_setprio(1);                                             \
  MROW(4,aA) MROW(5,aB) MROW(6,aC) MROW(7,aD)                                \
  __builtin_amdgcn_s_setprio(0);                                             \
  SBAR();                                                                    \
  if (PF){ gload16(Asrc + aoffg[0], dAp); gload16(Asrc + aoffg[1], dAp + 2048); } \
  bb0 = *(const bf16x8*)(pB +        c18);                                   \
  bb1 = *(const bf16x8*)(pB + 1024 + c18);                                   \
  bb2 = *(const bf16x8*)(pB + 2048 + c18);                                   \
  bb3 = *(const bf16x8*)(pB + 3072 + c18);                                   \
  aA  = *(const bf16x8*)(pA +        c18);                                   \
  aB  = *(const bf16x8*)(pA + 1024 + c18);                                   \
  aC  = *(const bf16x8*)(pA + 2048 + c18);                                   \
  aD  = *(const bf16x8*)(pA + 3072 + c18);                                   \
  SBAR();                                                                    \
  __builtin_amdgcn_s_setprio(1);                                             \
  MROW(0,aA) MROW(1,aB) MROW(2,aC) MROW(3,aD)                                \
  __builtin_amdgcn_s_setprio(0);                                             \
  SBAR();                                                                    \
  if (PF){ gload16(Asrc + aoffg[2], dAp + 4096); gload16(Asrc + aoffg[3], dAp + 6144); } \
  aA = *(const bf16x8*)(pA + 4096 + c18);                                    \
  aB = *(const bf16x8*)(pA + 5120 + c18);                                    \
  aC = *(const bf16x8*)(pA + 6144 + c18);                                    \
  aD = *(const bf16x8*)(pA + 7168 + c18);                                    \
  SBAR();                                                                    \
  __builtin_amdgcn_s_setprio(1);                                             \
  MROW(4,aA) MROW(5,aB) MROW(6,aC) MROW(7,aD)                                \
  __builtin_amdgcn_s_setprio(0);                                             \
  if (PF){ Asrc += 64; Bsrc += 64; }                                         \
  asm volatile("s_waitcnt vmcnt(" VB ")" ::: "memory");                      \
  SBAR();                                                                    \
}

  const int nkt = K >> 6;
#pragma unroll 1
  for (int it = 0; it < nkt - 2; it += 2){
    TILE(0,     1, "2", "2")
    TILE(32768, 1, "2", "2")
  }
  TILE(0,     1, "2", "2")
  TILE(32768, 0, "0", "0")

#undef TILE

  const int rr = h4*4;
  float* C = (float*)Cv + (size_t)bz*sCz
           + (size_t)(bx*256 + wr*128)*ldc + by*256 + wc*64;
#pragma unroll
  for (int n = 0; n < 4; ++n){
    const int col = n*16 + fr;
#pragma unroll
    for (int m = 0; m < 8; ++m)
#pragma unroll
      for (int j = 0; j < 4; ++j)
        C[(size_t)(m*16 + rr + j)*ldc + col] = acc[m][n][j];
  }
}

// ---------------------------------------------------------------------------
// info prep: hi/lo split (straight) + bf16 transpose, one read of info.
// grid: (M/64, D/64, B)
// ---------------------------------------------------------------------------
__global__ __launch_bounds__(256)
void k_prep_info(const float* __restrict__ V, short* __restrict__ hi,
                 short* __restrict__ lo, short* __restrict__ T,
                 const int MM, const int DD, const long sVz, const long sTz)
{
  __shared__ float t[64][65];
  const float* Vb = V + (long)blockIdx.z*sVz;
  short* hb = hi + (long)blockIdx.z*sVz;
  short* lb = lo + (long)blockIdx.z*sVz;
  short* Tb = T  + (long)blockIdx.z*sTz;
  const int m0 = blockIdx.x*64, d0 = blockIdx.y*64;
  const int tid = threadIdx.x;
#pragma unroll
  for (int i = 0; i < 4; ++i){
    const int c = tid + 256*i;
    const int r = c >> 4, c4 = (c & 15)*4;
    const float4 v = *(const float4*)(Vb + (size_t)(m0 + r)*DD + d0 + c4);
    t[r][c4+0]=v.x; t[r][c4+1]=v.y; t[r][c4+2]=v.z; t[r][c4+3]=v.w;
    const unsigned u0=fbits(v.x), u1=fbits(v.y), u2=fbits(v.z), u3=fbits(v.w);
    const size_t gi = (size_t)(m0 + r)*DD + d0 + c4;
    *(uint2*)(hb + gi) = make_uint2(pack_hi2(u0,u1), pack_hi2(u2,u3));
    const float l0 = v.x - bitsf(u0 & 0xffff0000u);
    const float l1 = v.y - bitsf(u1 & 0xffff0000u);
    const float l2 = v.z - bitsf(u2 & 0xffff0000u);
    const float l3 = v.w - bitsf(u3 & 0xffff0000u);
    *(uint2*)(lb + gi) = make_uint2(pack_rne2(l0,l1), pack_rne2(l2,l3));
  }
  __syncthreads();
#pragma unroll
  for (int i = 0; i < 4; ++i){
    const int c = tid + 256*i;
    const int d = c >> 4, m4 = (c & 15)*4;
    short4 o;
    o.x = bf_rne(t[m4+0][d]); o.y = bf_rne(t[m4+1][d]);
    o.z = bf_rne(t[m4+2][d]); o.w = bf_rne(t[m4+3][d]);
    *(short4*)(Tb + (size_t)(d0 + d)*MM + m0 + m4) = o;
  }
}

// ---------------------------------------------------------------------------
// Row softmax over 2048 fp32 logits; writes 2048 bf16 probs in place.
// grid: (S, nz), block 256.
// ---------------------------------------------------------------------------
__global__ __launch_bounds__(256)
void k_softmax_rows(float* __restrict__ Sb, const long sz)
{
  float* row = Sb + (long)blockIdx.y*sz + (long)blockIdx.x*2048;
  short* prow = (short*)row;
  const int tid = threadIdx.x;
  const int lane = tid & 63, wid = tid >> 6;

  const float4 v0 = *(const float4*)(row + tid*4);
  const float4 v1 = *(const float4*)(row + 1024 + tid*4);
  float x[8] = {v0.x, v0.y, v0.z, v0.w, v1.x, v1.y, v1.z, v1.w};

  float mx = x[0];
#pragma unroll
  for (int j = 1; j < 8; ++j) mx = fmaxf(mx, x[j]);
#pragma unroll
  for (int off = 32; off; off >>= 1) mx = fmaxf(mx, __shfl_xor(mx, off));

  __shared__ float red[8];
  if (lane == 0) red[wid] = mx;
  __syncthreads();
  mx = fmaxf(fmaxf(red[0], red[1]), fmaxf(red[2], red[3]));

  float e[8]; float s = 0.f;
#pragma unroll
  for (int j = 0; j < 8; ++j){ e[j] = __expf(x[j] - mx); s += e[j]; }
#pragma unroll
  for (int off = 32; off; off >>= 1) s += __shfl_xor(s, off);
  if (lane == 0) red[4 + wid] = s;
  __syncthreads();
  s = (red[4] + red[5]) + (red[6] + red[7]);
  const float inv = 1.0f / s;

  *(uint2*)(prow + tid*4)        = make_uint2(pack_rne2(e[0]*inv, e[1]*inv), pack_rne2(e[2]*inv, e[3]*inv));
  *(uint2*)(prow + 1024 + tid*4) = make_uint2(pack_rne2(e[4]*inv, e[5]*inv), pack_rne2(e[6]*inv, e[7]*inv));
}

// ---------------------------------------------------------------------------
extern "C" void kernel_launch(void* const* d_in, const int* in_sizes, int n_in,
                              void* d_out, int out_size, void* d_ws, size_t ws_size,
                              hipStream_t stream)
{
  const float* query = (const float*)d_in[0];   // [8,2048,1024]
  const float* info  = (const float*)d_in[1];   // [8,2048,1024]
  const float* Wm    = (const float*)d_in[2];   // [1024,1024]
  const float* bias  = (const float*)d_in[3];   // [1024]
  float* out = (float*)d_out;                   // [8,2048,1024]

  const int B = 8, S = 2048, M = 2048, D = 1024;
  const size_t PB = (size_t)S * D;

  // ws: info_hi | info_lo | infoT | W_hi | W_lo | Sbuf[nchunk * S*M fp32]
  short* info_hi = (short*)d_ws;
  short* info_lo = info_hi + 16777216;
  short* infoT   = info_lo + 16777216;
  short* W_hi    = infoT   + 16777216;
  short* W_lo    = W_hi    + 1048576;
  float* Sbuf    = (float*)(W_lo + 1048576);    // byte offset 104,857,600
  const size_t sb = (size_t)S * M * sizeof(float);
  size_t avail = ws_size > 104857600ull ? ws_size - 104857600ull : 0;
  int nchunk = (int)(avail / sb); if (nchunk > 8) nchunk = 8; if (nchunk < 1) nchunk = 1;

  // q as per-batch-interleaved hi/lo bf16 in d_out (consumed before overwrite)
  short* q_s = (short*)d_out;
  const long qBz = 2*(long)PB;
  const int  qLo = (int)PB;

  // W split
  k_split<<<1024, 256, 0, stream>>>(Wm, W_hi, W_lo, (long)(D*D/4));

  // K1: q = query @ W^T + b (fused hi/lo), query split staged in Sbuf
  int nb = 2*nchunk; if (nb > 8) nb = 8;
  for (int q0 = 0; q0 < B; q0 += nb){
    const int cur = (q0 + nb <= B) ? nb : (B - q0);
    short* qt_hi = (short*)Sbuf;
    short* qt_lo = qt_hi + (size_t)cur*PB;
    k_split<<<2048, 256, 0, stream>>>(query + (size_t)q0*PB, qt_hi, qt_lo,
                                      (long)((size_t)cur*PB/4));
    k_gemm3<true, true><<<dim3(S/256, D/256, cur), 512, 0, stream>>>(
        qt_hi, qt_lo, W_hi, W_lo, q_s + (size_t)q0*qBz, bias,
        D, D, D, D, (long)PB, 0L, qBz, qLo);
  }

  // info: hi/lo split + bf16 transpose in one pass
  k_prep_info<<<dim3(M/64, D/64, B), 256, 0, stream>>>(
      info, info_hi, info_lo, infoT, M, D, (long)PB, (long)PB);

  // chunked K2 -> K3 -> K4
  for (int b0 = 0; b0 < B; b0 += nchunk){
    const int cur = (b0 + nchunk <= B) ? nchunk : (B - b0);

    // K2: logits = q @ info^T (fused hi/lo) -> Sbuf fp32
    const short* qh = q_s + (size_t)b0*qBz;
    k_gemm3<false, false><<<dim3(S/256, M/256, cur), 512, 0, stream>>>(
        qh, qh + qLo, info_hi + (size_t)b0*PB, info_lo + (size_t)b0*PB,
        Sbuf, nullptr, D, D, D, M, qBz, (long)PB, (long)S*M, 0);

    // K3: row softmax, bf16 P in place (row stride 4096 shorts)
    k_softmax_rows<<<dim3(S, cur), 256, 0, stream>>>(Sbuf, (long)S*M);

    // K4: out = P @ info (P bf16, lda 4096 shorts; B = infoT)
    k_gemm1<<<dim3(S/256, D/256, cur), 512, 0, stream>>>(
        (const short*)Sbuf, infoT + (size_t)b0*PB,
        out + (size_t)b0*PB, M, 2*M, M, D,
        (long)(2*(size_t)S*M), (long)PB, (long)S*D);
  }
}

// Round 15
// 437.462 us; speedup vs baseline: 1.0320x; 1.0320x over previous
//
#include <hip/hip_runtime.h>

#define DEVI __device__ __forceinline__

typedef __attribute__((ext_vector_type(4))) float f32x4;
typedef __attribute__((ext_vector_type(8))) short bf16x8;

typedef const unsigned __attribute__((address_space(1))) as1_u32;
typedef unsigned __attribute__((address_space(3))) as3_u32;

DEVI unsigned fbits(float x){ union{float f;unsigned u;} v; v.f=x; return v.u; }
DEVI float bitsf(unsigned u){ union{unsigned u;float f;} v; v.u=u; return v.f; }
DEVI short bf_rne(float x){ unsigned u=fbits(x); u += 0x7fffu + ((u>>16)&1u); return (short)(u>>16); }

DEVI unsigned pack_hi2(unsigned u0, unsigned u1){
#if __has_builtin(__builtin_amdgcn_perm)
  return __builtin_amdgcn_perm(u1, u0, 0x07060302u);
#else
  return (u0 >> 16) | (u1 & 0xffff0000u);
#endif
}
DEVI unsigned pack_rne2(float a, float b){
  return (unsigned)(unsigned short)bf_rne(a) | ((unsigned)(unsigned short)bf_rne(b) << 16);
}

DEVI void gload16(const short* g, short* s){
  __builtin_amdgcn_global_load_lds((as1_u32*)g, (as3_u32*)s, 16, 0, 0);
}

#define SBAR() { __builtin_amdgcn_sched_barrier(0); asm volatile("" ::: "memory"); \
                 __builtin_amdgcn_s_barrier(); __builtin_amdgcn_sched_barrier(0); }

#define MF(a,b,c) __builtin_amdgcn_mfma_f32_16x16x32_bf16(a,b,c,0,0,0)
#define MROW(M, x) \
  acc[M][0] = MF(x, bb0, acc[M][0]); \
  acc[M][1] = MF(x, bb1, acc[M][1]); \
  acc[M][2] = MF(x, bb2, acc[M][2]); \
  acc[M][3] = MF(x, bb3, acc[M][3]);

// ---------------------------------------------------------------------------
// Split fp32 -> (hi = bf16 truncation, lo = bf16_rne(x - hi)).
// ---------------------------------------------------------------------------
__global__ __launch_bounds__(256)
void k_split(const float* __restrict__ in, short* __restrict__ hi,
             short* __restrict__ lo, const long n4)
{
  long i = (long)blockIdx.x*256 + threadIdx.x;
  const long stride = (long)gridDim.x*256;
  for (; i < n4; i += stride){
    const float4 v = ((const float4*)in)[i];
    const unsigned u0=fbits(v.x), u1=fbits(v.y), u2=fbits(v.z), u3=fbits(v.w);
    ((uint2*)hi)[i] = make_uint2(pack_hi2(u0,u1), pack_hi2(u2,u3));
    const float l0 = v.x - bitsf(u0 & 0xffff0000u);
    const float l1 = v.y - bitsf(u1 & 0xffff0000u);
    const float l2 = v.z - bitsf(u2 & 0xffff0000u);
    const float l3 = v.w - bitsf(u3 & 0xffff0000u);
    ((uint2*)lo)[i] = make_uint2(pack_rne2(l0,l1), pack_rne2(l2,l3));
  }
}

// ---------------------------------------------------------------------------
// Fused 3-combo hi/lo GEMM: 3 phases (AhBh, AlBh, AhBl) per BK=32 k-step.
// 256x256 tile, 512 thr (8 waves 2x4), per-wave 128x64, dbuf 128KB LDS.
// Chunk-XOR swizzle: LDS slot c of row r holds logical chunk c^((r>>1)&3);
// read side folds inverse into per-lane-constant base -> 0 bank conflicts.
// Counted vmcnt(4/6/8), never 0 in-loop; staged hi4 at P0 / lo4 at P1
// (load-balances the memory pipe — R11's all-8-at-P0 variant regressed).
// SESSION BEST (R6/R10): 439 us total, K2 179 us @ MfmaUtil 50.3%.
// ---------------------------------------------------------------------------
template<bool BIAS, bool SPLIT_OUT>
__global__ __launch_bounds__(512, 2)
void k_gemm3(const short* __restrict__ Ah, const short* __restrict__ Al,
             const short* __restrict__ Bh, const short* __restrict__ Bl,
             void* __restrict__ Cv, const float* __restrict__ bias,
             const int K, const int lda, const int ldb, const int ldc,
             const long sAz, const long sBz, const long sCz, const int loOff)
{
  // per buffer (shorts): Ah [0,8192) Al [8192,16384) Bh [16384,24576) Bl [24576,32768)
  __shared__ short LDS[65536];   // 2 buffers x 64KB = 128 KiB

  const int tid = threadIdx.x;
  const int w = tid >> 6, l = tid & 63;
  const int wr = w >> 2, wc = w & 3;
  const int fr = l & 15, h4 = l >> 4;
  const long bz = blockIdx.z;

  // XCD-aware bijective swizzle (nwg % 8 == 0 for all our grids)
  const int nwg = gridDim.x * gridDim.y;
  const int xy  = blockIdx.y * gridDim.x + blockIdx.x;
  const int q8  = nwg >> 3;
  const int sw  = (xy & 7) * q8 + (xy >> 3);
  const int bx  = sw % gridDim.x;
  const int by  = sw / gridDim.x;

  const size_t aOff = (size_t)bz*sAz + (size_t)bx*256*lda;
  const size_t bOff = (size_t)bz*sBz + (size_t)by*256*ldb;

  // staging: 16KB tile = 1024 x 16B chunks; thread handles chunks c0, c0+512.
  // chunk ci -> row ci>>2; LDS slot ci&3 holds logical k-chunk
  // (ci&3)^((ci>>3)&3)  [inverse-swizzled global source, linear LDS dest]
  const int c0 = w*64 + l, c1 = c0 + 512;
  const int k0 = ((c0 & 3) ^ ((c0 >> 3) & 3)) * 8;
  const int k1 = ((c1 & 3) ^ ((c1 >> 3) & 3)) * 8;
  const size_t a0 = (size_t)(c0 >> 2)*lda + k0;
  const size_t a1 = (size_t)(c1 >> 2)*lda + k1;
  const size_t b0 = (size_t)(c0 >> 2)*ldb + k0;
  const size_t b1 = (size_t)(c1 >> 2)*ldb + k1;
  const int dS0 = w*512, dS1 = 4096 + w*512;

  // fragment read bases (shorts): row stride 32; swizzled chunk per lane.
  // chunk = h4 ^ ((row>>1)&3); row = base + m*16 + fr with base,m*16 ≡ 0 mod 8
  // so the XOR term depends only on fr -> constant per lane for all frags.
  const int cswz = (h4 ^ ((fr >> 1) & 3)) << 3;
  const int rbA = (wr*128 + fr)*32 + cswz;
  const int rbB = 16384 + (wc*64 + fr)*32 + cswz;

  f32x4 acc[8][4];
#pragma unroll
  for (int m = 0; m < 8; ++m)
#pragma unroll
    for (int n = 0; n < 4; ++n){ acc[m][n][0]=0.f; acc[m][n][1]=0.f; acc[m][n][2]=0.f; acc[m][n][3]=0.f; }

  const short* pAh = Ah + aOff;
  const short* pAl = Al + aOff;
  const short* pBh = Bh + bOff;
  const short* pBl = Bl + bOff;

  // ---- prologue: stage step 0 into buf0 (order: Ah,Ah,Bh,Bh,Al,Al,Bl,Bl) ----
  gload16(pAh + a0, LDS + dS0);
  gload16(pAh + a1, LDS + dS1);
  gload16(pBh + b0, LDS + 16384 + dS0);
  gload16(pBh + b1, LDS + 16384 + dS1);
  gload16(pAl + a0, LDS + 8192 + dS0);
  gload16(pAl + a1, LDS + 8192 + dS1);
  gload16(pBl + b0, LDS + 24576 + dS0);
  gload16(pBl + b1, LDS + 24576 + dS1);
  pAh += 32; pAl += 32; pBh += 32; pBl += 32;

#define STEP3(CO, PF, V1, V2, V3)                                            \
{                                                                            \
  const short* pA = LDS + (CO) + rbA;                                        \
  const short* pB = LDS + (CO) + rbB;                                        \
  short* dst = LDS + ((CO) ^ 32768);                                         \
  bf16x8 ah0,ah1,ah2,ah3,ah4,ah5,ah6,ah7, bb0,bb1,bb2,bb3;                   \
  /* P0: Ah x Bh */                                                          \
  asm volatile("s_waitcnt vmcnt(" V1 ")" ::: "memory");                      \
  SBAR();                                                                    \
  if (PF){ gload16(pAh + a0, dst + dS0);                                     \
           gload16(pAh + a1, dst + dS1);                                     \
           gload16(pBh + b0, dst + 16384 + dS0);                             \
           gload16(pBh + b1, dst + 16384 + dS1); }                           \
  bb0 = *(const bf16x8*)(pB);                                                \
  bb1 = *(const bf16x8*)(pB + 512);                                          \
  bb2 = *(const bf16x8*)(pB + 1024);                                         \
  bb3 = *(const bf16x8*)(pB + 1536);                                         \
  ah0 = *(const bf16x8*)(pA);                                                \
  ah1 = *(const bf16x8*)(pA + 512);                                          \
  ah2 = *(const bf16x8*)(pA + 1024);                                         \
  ah3 = *(const bf16x8*)(pA + 1536);                                         \
  ah4 = *(const bf16x8*)(pA + 2048);                                         \
  ah5 = *(const bf16x8*)(pA + 2560);                                         \
  ah6 = *(const bf16x8*)(pA + 3072);                                         \
  ah7 = *(const bf16x8*)(pA + 3584);                                         \
  __builtin_amdgcn_s_setprio(1);                                             \
  MROW(0,ah0) MROW(1,ah1) MROW(2,ah2) MROW(3,ah3)                            \
  MROW(4,ah4) MROW(5,ah5) MROW(6,ah6) MROW(7,ah7)                            \
  __builtin_amdgcn_s_setprio(0);                                             \
  /* P1: Al x Bh */                                                          \
  asm volatile("s_waitcnt vmcnt(" V2 ")" ::: "memory");                      \
  SBAR();                                                                    \
  if (PF){ gload16(pAl + a0, dst + 8192 + dS0);                              \
           gload16(pAl + a1, dst + 8192 + dS1);                              \
           gload16(pBl + b0, dst + 24576 + dS0);                             \
           gload16(pBl + b1, dst + 24576 + dS1);                             \
           pAh += 32; pAl += 32; pBh += 32; pBl += 32; }                     \
  {                                                                          \
    bf16x8 al0 = *(const bf16x8*)(pA + 8192);                                \
    bf16x8 al1 = *(const bf16x8*)(pA + 8192 + 512);                          \
    bf16x8 al2 = *(const bf16x8*)(pA + 8192 + 1024);                         \
    bf16x8 al3 = *(const bf16x8*)(pA + 8192 + 1536);                         \
    bf16x8 al4 = *(const bf16x8*)(pA + 8192 + 2048);                         \
    bf16x8 al5 = *(const bf16x8*)(pA + 8192 + 2560);                         \
    bf16x8 al6 = *(const bf16x8*)(pA + 8192 + 3072);                         \
    bf16x8 al7 = *(const bf16x8*)(pA + 8192 + 3584);                         \
    __builtin_amdgcn_s_setprio(1);                                           \
    MROW(0,al0) MROW(1,al1) MROW(2,al2) MROW(3,al3)                          \
    MROW(4,al4) MROW(5,al5) MROW(6,al6) MROW(7,al7)                          \
    __builtin_amdgcn_s_setprio(0);                                           \
  }                                                                          \
  /* P2: Ah x Bl (Ah frags still in regs) */                                 \
  asm volatile("s_waitcnt vmcnt(" V3 ")" ::: "memory");                      \
  SBAR();                                                                    \
  bb0 = *(const bf16x8*)(pB + 8192);                                         \
  bb1 = *(const bf16x8*)(pB + 8192 + 512);                                   \
  bb2 = *(const bf16x8*)(pB + 8192 + 1024);                                  \
  bb3 = *(const bf16x8*)(pB + 8192 + 1536);                                  \
  __builtin_amdgcn_s_setprio(1);                                             \
  MROW(0,ah0) MROW(1,ah1) MROW(2,ah2) MROW(3,ah3)                            \
  MROW(4,ah4) MROW(5,ah5) MROW(6,ah6) MROW(7,ah7)                            \
  __builtin_amdgcn_s_setprio(0);                                             \
}

  const int nk = K >> 5;   // k-steps of 32 (even for all our K)
#pragma unroll 1
  for (int it = 0; it < nk - 2; it += 2){
    STEP3(0,     1, "4", "6", "8")
    STEP3(32768, 1, "4", "6", "8")
  }
  STEP3(0,     1, "4", "6", "8")
  STEP3(32768, 0, "4", "2", "0")

#undef STEP3

  // ---- epilogue: C/D layout col = lane&15, row = (lane>>4)*4 + j ----
  const int rr = h4*4;
  if constexpr (SPLIT_OUT){
    short* Ch = (short*)Cv + (size_t)bz*sCz
              + (size_t)(bx*256 + wr*128)*ldc + by*256 + wc*64;
    short* Cl = Ch + loOff;
#pragma unroll
    for (int n = 0; n < 4; ++n){
      const int col = n*16 + fr;
      const float bv = BIAS ? bias[by*256 + wc*64 + col] : 0.f;
#pragma unroll
      for (int m = 0; m < 8; ++m)
#pragma unroll
        for (int j = 0; j < 4; ++j){
          const float v = acc[m][n][j] + bv;
          const unsigned uh = fbits(v) & 0xffff0000u;
          const size_t idx = (size_t)(m*16 + rr + j)*ldc + col;
          Ch[idx] = (short)(uh >> 16);
          Cl[idx] = bf_rne(v - bitsf(uh));
        }
    }
  } else {
    float* C = (float*)Cv + (size_t)bz*sCz
             + (size_t)(bx*256 + wr*128)*ldc + by*256 + wc*64;
#pragma unroll
    for (int n = 0; n < 4; ++n){
      const int col = n*16 + fr;
      const float bv = BIAS ? bias[by*256 + wc*64 + col] : 0.f;
#pragma unroll
      for (int m = 0; m < 8; ++m)
#pragma unroll
        for (int j = 0; j < 4; ++j)
          C[(size_t)(m*16 + rr + j)*ldc + col] = acc[m][n][j] + bv;
    }
  }
}

// ---------------------------------------------------------------------------
// Plain bf16 1-pass GEMM (K4): R3/R6-proven 8-phase 256x256 BK=64 structure
// with st_16x32 swizzle + counted vmcnt (0 bank conflicts measured).
// ---------------------------------------------------------------------------
__global__ __launch_bounds__(512, 2)
void k_gemm1(const short* __restrict__ Ah, const short* __restrict__ Bh,
             void* __restrict__ Cv,
             const int K, const int lda, const int ldb, const int ldc,
             const long sAz, const long sBz, const long sCz)
{
  __shared__ short LDS[65536];

  const int tid = threadIdx.x;
  const int w = tid >> 6, l = tid & 63;
  const int wr = w >> 2, wc = w & 3;
  const int fr = l & 15, h4 = l >> 4;
  const long bz = blockIdx.z;

  const int nwg = gridDim.x * gridDim.y;
  const int xy  = blockIdx.y * gridDim.x + blockIdx.x;
  const int q8  = nwg >> 3;
  const int sw  = (xy & 7) * q8 + (xy >> 3);
  const int bx  = sw % gridDim.x;
  const int by  = sw / gridDim.x;

  const size_t aOff = (size_t)bz*sAz + (size_t)bx*256*lda;
  const size_t bOff = (size_t)bz*sBz + (size_t)by*256*ldb;

  const int sch = (((l & 7) ^ ((l >> 3) & 7)) << 3);
  const int rA0 = wr*128 + (w & 3)*8 + (l >> 3);
  int aoffg[4];
#pragma unroll
  for (int q2 = 0; q2 < 4; ++q2) aoffg[q2] = (rA0 + 32*q2)*lda;
  const int rB0 = wc*64 + (w >> 2)*8 + (l >> 3);
  int boffg[4];
#pragma unroll
  for (int j2 = 0; j2 < 4; ++j2) boffg[j2] = (rB0 + 16*j2)*ldb;
  const int dAu = wr*8192 + (w & 3)*512;
  const int dBu = 16384 + wc*4096 + (w >> 2)*512;

  const int rbA = (wr*128 + fr)*64;
  const int rbB = 16384 + (wc*64 + fr)*64;
  const int c08 = ((h4     ) ^ (l & 7)) << 3;
  const int c18 = ((h4 + 4 ) ^ (l & 7)) << 3;

  f32x4 acc[8][4];
#pragma unroll
  for (int m = 0; m < 8; ++m)
#pragma unroll
    for (int n = 0; n < 4; ++n){ acc[m][n][0]=0.f; acc[m][n][1]=0.f; acc[m][n][2]=0.f; acc[m][n][3]=0.f; }

  const short* Asrc = Ah + aOff + sch;
  const short* Bsrc = Bh + bOff + sch;

  {
    short* dB0 = LDS + dBu;
    short* dA0 = LDS + dAu;
    gload16(Bsrc + boffg[0], dB0);
    gload16(Bsrc + boffg[1], dB0 + 1024);
    gload16(Bsrc + boffg[2], dB0 + 2048);
    gload16(Bsrc + boffg[3], dB0 + 3072);
    gload16(Asrc + aoffg[0], dA0);
    gload16(Asrc + aoffg[1], dA0 + 2048);
    gload16(Asrc + aoffg[2], dA0 + 4096);
    gload16(Asrc + aoffg[3], dA0 + 6144);
  }
  Asrc += 64; Bsrc += 64;
  asm volatile("s_waitcnt vmcnt(2)" ::: "memory");
  SBAR();

#define TILE(CO, PF, VA, VB)                                                 \
{                                                                            \
  const short* pA = LDS + (CO) + rbA;                                        \
  const short* pB = LDS + (CO) + rbB;                                        \
  short* dAp = LDS + ((CO)^32768) + dAu;                                     \
  short* dBp = LDS + ((CO)^32768) + dBu;                                     \
  bf16x8 aA,aB,aC,aD, bb0,bb1,bb2,bb3;                                       \
  if (PF){ gload16(Bsrc + boffg[0], dBp); gload16(Bsrc + boffg[1], dBp + 1024); } \
  bb0 = *(const bf16x8*)(pB +        c08);                                   \
  bb1 = *(const bf16x8*)(pB + 1024 + c08);                                   \
  bb2 = *(const bf16x8*)(pB + 2048 + c08);                                   \
  bb3 = *(const bf16x8*)(pB + 3072 + c08);                                   \
  aA  = *(const bf16x8*)(pA +        c08);                                   \
  aB  = *(const bf16x8*)(pA + 1024 + c08);                                   \
  aC  = *(const bf16x8*)(pA + 2048 + c08);                                   \
  aD  = *(const bf16x8*)(pA + 3072 + c08);                                   \
  SBAR();                                                                    \
  __builtin_amdgcn_s_setprio(1);                                             \
  MROW(0,aA) MROW(1,aB) MROW(2,aC) MROW(3,aD)                                \
  __builtin_amdgcn_s_setprio(0);                                             \
  asm volatile("s_waitcnt vmcnt(" VA ")" ::: "memory");                      \
  SBAR();                                                                    \
  if (PF){ gload16(Bsrc + boffg[2], dBp + 2048); gload16(Bsrc + boffg[3], dBp + 3072); } \
  aA = *(const bf16x8*)(pA + 4096 + c08);                                    \
  aB = *(const bf16x8*)(pA + 5120 + c08);                                    \
  aC = *(const bf16x8*)(pA + 6144 + c08);                                    \
  aD = *(const bf16x8*)(pA + 7168 + c08);                                    \
  SBAR();                                                                    \
  __builtin_amdgcn_s_setprio(1);                                             \
  MROW(4,aA) MROW(5,aB) MROW(6,aC) MROW(7,aD)                                \
  __builtin_amdgcn_s_setprio(0);                                             \
  SBAR();                                                                    \
  if (PF){ gload16(Asrc + aoffg[0], dAp); gload16(Asrc + aoffg[1], dAp + 2048); } \
  bb0 = *(const bf16x8*)(pB +        c18);                                   \
  bb1 = *(const bf16x8*)(pB + 1024 + c18);                                   \
  bb2 = *(const bf16x8*)(pB + 2048 + c18);                                   \
  bb3 = *(const bf16x8*)(pB + 3072 + c18);                                   \
  aA  = *(const bf16x8*)(pA +        c18);                                   \
  aB  = *(const bf16x8*)(pA + 1024 + c18);                                   \
  aC  = *(const bf16x8*)(pA + 2048 + c18);                                   \
  aD  = *(const bf16x8*)(pA + 3072 + c18);                                   \
  SBAR();                                                                    \
  __builtin_amdgcn_s_setprio(1);                                             \
  MROW(0,aA) MROW(1,aB) MROW(2,aC) MROW(3,aD)                                \
  __builtin_amdgcn_s_setprio(0);                                             \
  SBAR();                                                                    \
  if (PF){ gload16(Asrc + aoffg[2], dAp + 4096); gload16(Asrc + aoffg[3], dAp + 6144); } \
  aA = *(const bf16x8*)(pA + 4096 + c18);                                    \
  aB = *(const bf16x8*)(pA + 5120 + c18);                                    \
  aC = *(const bf16x8*)(pA + 6144 + c18);                                    \
  aD = *(const bf16x8*)(pA + 7168 + c18);                                    \
  SBAR();                                                                    \
  __builtin_amdgcn_s_setprio(1);                                             \
  MROW(4,aA) MROW(5,aB) MROW(6,aC) MROW(7,aD)                                \
  __builtin_amdgcn_s_setprio(0);                                             \
  if (PF){ Asrc += 64; Bsrc += 64; }                                         \
  asm volatile("s_waitcnt vmcnt(" VB ")" ::: "memory");                      \
  SBAR();                                                                    \
}

  const int nkt = K >> 6;
#pragma unroll 1
  for (int it = 0; it < nkt - 2; it += 2){
    TILE(0,     1, "2", "2")
    TILE(32768, 1, "2", "2")
  }
  TILE(0,     1, "2", "2")
  TILE(32768, 0, "0", "0")

#undef TILE

  const int rr = h4*4;
  float* C = (float*)Cv + (size_t)bz*sCz
           + (size_t)(bx*256 + wr*128)*ldc + by*256 + wc*64;
#pragma unroll
  for (int n = 0; n < 4; ++n){
    const int col = n*16 + fr;
#pragma unroll
    for (int m = 0; m < 8; ++m)
#pragma unroll
      for (int j = 0; j < 4; ++j)
        C[(size_t)(m*16 + rr + j)*ldc + col] = acc[m][n][j];
  }
}

// ---------------------------------------------------------------------------
// info prep: hi/lo split (straight) + bf16 transpose, one read of info.
// grid: (M/64, D/64, B)
// ---------------------------------------------------------------------------
__global__ __launch_bounds__(256)
void k_prep_info(const float* __restrict__ V, short* __restrict__ hi,
                 short* __restrict__ lo, short* __restrict__ T,
                 const int MM, const int DD, const long sVz, const long sTz)
{
  __shared__ float t[64][65];
  const float* Vb = V + (long)blockIdx.z*sVz;
  short* hb = hi + (long)blockIdx.z*sVz;
  short* lb = lo + (long)blockIdx.z*sVz;
  short* Tb = T  + (long)blockIdx.z*sTz;
  const int m0 = blockIdx.x*64, d0 = blockIdx.y*64;
  const int tid = threadIdx.x;
#pragma unroll
  for (int i = 0; i < 4; ++i){
    const int c = tid + 256*i;
    const int r = c >> 4, c4 = (c & 15)*4;
    const float4 v = *(const float4*)(Vb + (size_t)(m0 + r)*DD + d0 + c4);
    t[r][c4+0]=v.x; t[r][c4+1]=v.y; t[r][c4+2]=v.z; t[r][c4+3]=v.w;
    const unsigned u0=fbits(v.x), u1=fbits(v.y), u2=fbits(v.z), u3=fbits(v.w);
    const size_t gi = (size_t)(m0 + r)*DD + d0 + c4;
    *(uint2*)(hb + gi) = make_uint2(pack_hi2(u0,u1), pack_hi2(u2,u3));
    const float l0 = v.x - bitsf(u0 & 0xffff0000u);
    const float l1 = v.y - bitsf(u1 & 0xffff0000u);
    const float l2 = v.z - bitsf(u2 & 0xffff0000u);
    const float l3 = v.w - bitsf(u3 & 0xffff0000u);
    *(uint2*)(lb + gi) = make_uint2(pack_rne2(l0,l1), pack_rne2(l2,l3));
  }
  __syncthreads();
#pragma unroll
  for (int i = 0; i < 4; ++i){
    const int c = tid + 256*i;
    const int d = c >> 4, m4 = (c & 15)*4;
    short4 o;
    o.x = bf_rne(t[m4+0][d]); o.y = bf_rne(t[m4+1][d]);
    o.z = bf_rne(t[m4+2][d]); o.w = bf_rne(t[m4+3][d]);
    *(short4*)(Tb + (size_t)(d0 + d)*MM + m0 + m4) = o;
  }
}

// ---------------------------------------------------------------------------
// Row softmax over 2048 fp32 logits; writes 2048 bf16 probs in place.
// grid: (S, nz), block 256.
// ---------------------------------------------------------------------------
__global__ __launch_bounds__(256)
void k_softmax_rows(float* __restrict__ Sb, const long sz)
{
  float* row = Sb + (long)blockIdx.y*sz + (long)blockIdx.x*2048;
  short* prow = (short*)row;
  const int tid = threadIdx.x;
  const int lane = tid & 63, wid = tid >> 6;

  const float4 v0 = *(const float4*)(row + tid*4);
  const float4 v1 = *(const float4*)(row + 1024 + tid*4);
  float x[8] = {v0.x, v0.y, v0.z, v0.w, v1.x, v1.y, v1.z, v1.w};

  float mx = x[0];
#pragma unroll
  for (int j = 1; j < 8; ++j) mx = fmaxf(mx, x[j]);
#pragma unroll
  for (int off = 32; off; off >>= 1) mx = fmaxf(mx, __shfl_xor(mx, off));

  __shared__ float red[8];
  if (lane == 0) red[wid] = mx;
  __syncthreads();
  mx = fmaxf(fmaxf(red[0], red[1]), fmaxf(red[2], red[3]));

  float e[8]; float s = 0.f;
#pragma unroll
  for (int j = 0; j < 8; ++j){ e[j] = __expf(x[j] - mx); s += e[j]; }
#pragma unroll
  for (int off = 32; off; off >>= 1) s += __shfl_xor(s, off);
  if (lane == 0) red[4 + wid] = s;
  __syncthreads();
  s = (red[4] + red[5]) + (red[6] + red[7]);
  const float inv = 1.0f / s;

  *(uint2*)(prow + tid*4)        = make_uint2(pack_rne2(e[0]*inv, e[1]*inv), pack_rne2(e[2]*inv, e[3]*inv));
  *(uint2*)(prow + 1024 + tid*4) = make_uint2(pack_rne2(e[4]*inv, e[5]*inv), pack_rne2(e[6]*inv, e[7]*inv));
}

// ---------------------------------------------------------------------------
extern "C" void kernel_launch(void* const* d_in, const int* in_sizes, int n_in,
                              void* d_out, int out_size, void* d_ws, size_t ws_size,
                              hipStream_t stream)
{
  const float* query = (const float*)d_in[0];   // [8,2048,1024]
  const float* info  = (const float*)d_in[1];   // [8,2048,1024]
  const float* Wm    = (const float*)d_in[2];   // [1024,1024]
  const float* bias  = (const float*)d_in[3];   // [1024]
  float* out = (float*)d_out;                   // [8,2048,1024]

  const int B = 8, S = 2048, M = 2048, D = 1024;
  const size_t PB = (size_t)S * D;

  // ws: info_hi | info_lo | infoT | W_hi | W_lo | Sbuf[nchunk * S*M fp32]
  short* info_hi = (short*)d_ws;
  short* info_lo = info_hi + 16777216;
  short* infoT   = info_lo + 16777216;
  short* W_hi    = infoT   + 16777216;
  short* W_lo    = W_hi    + 1048576;
  float* Sbuf    = (float*)(W_lo + 1048576);    // byte offset 104,857,600
  const size_t sb = (size_t)S * M * sizeof(float);
  size_t avail = ws_size > 104857600ull ? ws_size - 104857600ull : 0;
  int nchunk = (int)(avail / sb); if (nchunk > 8) nchunk = 8; if (nchunk < 1) nchunk = 1;

  // q as per-batch-interleaved hi/lo bf16 in d_out (consumed before overwrite)
  short* q_s = (short*)d_out;
  const long qBz = 2*(long)PB;
  const int  qLo = (int)PB;

  // W split
  k_split<<<1024, 256, 0, stream>>>(Wm, W_hi, W_lo, (long)(D*D/4));

  // K1: q = query @ W^T + b (fused hi/lo), query split staged in Sbuf
  int nb = 2*nchunk; if (nb > 8) nb = 8;
  for (int q0 = 0; q0 < B; q0 += nb){
    const int cur = (q0 + nb <= B) ? nb : (B - q0);
    short* qt_hi = (short*)Sbuf;
    short* qt_lo = qt_hi + (size_t)cur*PB;
    k_split<<<2048, 256, 0, stream>>>(query + (size_t)q0*PB, qt_hi, qt_lo,
                                      (long)((size_t)cur*PB/4));
    k_gemm3<true, true><<<dim3(S/256, D/256, cur), 512, 0, stream>>>(
        qt_hi, qt_lo, W_hi, W_lo, q_s + (size_t)q0*qBz, bias,
        D, D, D, D, (long)PB, 0L, qBz, qLo);
  }

  // info: hi/lo split + bf16 transpose in one pass
  k_prep_info<<<dim3(M/64, D/64, B), 256, 0, stream>>>(
      info, info_hi, info_lo, infoT, M, D, (long)PB, (long)PB);

  // chunked K2 -> K3 -> K4
  for (int b0 = 0; b0 < B; b0 += nchunk){
    const int cur = (b0 + nchunk <= B) ? nchunk : (B - b0);

    // K2: logits = q @ info^T (fused hi/lo) -> Sbuf fp32
    const short* qh = q_s + (size_t)b0*qBz;
    k_gemm3<false, false><<<dim3(S/256, M/256, cur), 512, 0, stream>>>(
        qh, qh + qLo, info_hi + (size_t)b0*PB, info_lo + (size_t)b0*PB,
        Sbuf, nullptr, D, D, D, M, qBz, (long)PB, (long)S*M, 0);

    // K3: row softmax, bf16 P in place (row stride 4096 shorts)
    k_softmax_rows<<<dim3(S, cur), 256, 0, stream>>>(Sbuf, (long)S*M);

    // K4: out = P @ info (P bf16, lda 4096 shorts; B = infoT)
    k_gemm1<<<dim3(S/256, D/256, cur), 512, 0, stream>>>(
        (const short*)Sbuf, infoT + (size_t)b0*PB,
        out + (size_t)b0*PB, M, 2*M, M, D,
        (long)(2*(size_t)S*M), (long)PB, (long)S*D);
  }
}